// Round 3
// baseline (116.901 us; speedup 1.0000x reference)
//
#include <hip/hip_runtime.h>

#define NB 4096
#define DK 1024
#define EPSF 1e-6f
#define QS 32.0f          // fp4 pre-scale 2^5: normalized entries sigma=1/32 -> sigma=1

typedef __attribute__((ext_vector_type(8))) int   i32x8_t;
typedef __attribute__((ext_vector_type(4))) int   i32x4_t;
typedef __attribute__((ext_vector_type(4))) float f32x4_t;

#if defined(__has_builtin)
#if __has_builtin(__builtin_amdgcn_cvt_scalef32_pk_fp4_f32)
#define HW_FP4 1
#endif
#endif

// ---------------------------------------------------------------------------
// Global fp4 layout (LINEAR, r3: swizzle dropped — no LDS anywhere, so no
// bank concerns): row,k -> panel p=row>>4, r=row&15, kb=k>>7:
//   byte offset = p*8192 + kb*1024 + r*64 + (k&127)/2, nibble k&1.
// A (p,kb) chunk is 1 KB: 16 rows x 64 B. A wave reads a 16x128-k fragment as
// lane l -> 16 B at r=l&15, slot q=l>>4: chunk + r*64 + q*16 (line-coalesced).
// ---------------------------------------------------------------------------

// branchless e2m1 encode fallback: grid 0,.5,1,1.5,2,3,4,6.
__device__ __forceinline__ unsigned enc4(float v) {
    const float a = fabsf(v);
    unsigned c = (a >= 0.25f) + (a >= 0.75f) + (a >= 1.25f) + (a >= 1.75f)
               + (a >= 2.5f)  + (a >= 3.5f)  + (a >= 5.0f);
    return c | ((v < 0.f) ? 8u : 0u);
}

// ---------------------------------------------------------------------------
// Kernel 1: wave-per-row normalize -> fp4 e2m1 (x32), linear layout;
// exact fp32 diagonal; zeroes rowsum/colsum. Lane l owns k[16l,16l+16) ->
// 16 nibbles = 8 B at chunk + r*64 + (l&7)*8, one dwordx2 store per matrix.
// ---------------------------------------------------------------------------
__global__ __launch_bounds__(256) void normalize_rows(
    const float* __restrict__ x, const float* __restrict__ y,
    unsigned char* __restrict__ xq, unsigned char* __restrict__ yq,
    float* __restrict__ sdiag, float* __restrict__ zerobuf)
{
    const int t = threadIdx.x;
    const int gid = blockIdx.x * 256 + t;
    if (gid < 2 * NB) zerobuf[gid] = 0.f;   // rowsum+colsum contiguous

    const int wave = t >> 6;
    const int lane = t & 63;
    const int row  = blockIdx.x * 4 + wave;

    const float4* xr = reinterpret_cast<const float4*>(x + (size_t)row * DK);
    const float4* yr = reinterpret_cast<const float4*>(y + (size_t)row * DK);

    float4 xv[4], yv[4];
    float ssx = 0.f, ssy = 0.f, sxy = 0.f;
    #pragma unroll
    for (int jj = 0; jj < 4; ++jj) {
        xv[jj] = xr[lane * 4 + jj];
        yv[jj] = yr[lane * 4 + jj];
        ssx += xv[jj].x*xv[jj].x + xv[jj].y*xv[jj].y + xv[jj].z*xv[jj].z + xv[jj].w*xv[jj].w;
        ssy += yv[jj].x*yv[jj].x + yv[jj].y*yv[jj].y + yv[jj].z*yv[jj].z + yv[jj].w*yv[jj].w;
        sxy += xv[jj].x*yv[jj].x + xv[jj].y*yv[jj].y + xv[jj].z*yv[jj].z + xv[jj].w*yv[jj].w;
    }
    #pragma unroll
    for (int off = 1; off < 64; off <<= 1) {
        ssx += __shfl_xor(ssx, off, 64);
        ssy += __shfl_xor(ssy, off, 64);
        sxy += __shfl_xor(sxy, off, 64);
    }
    const float invx = 1.0f / fmaxf(sqrtf(ssx), EPSF);
    const float invy = 1.0f / fmaxf(sqrtf(ssy), EPSF);
    const float sx = invx * QS;
    const float sy = invy * QS;

    float fx[16], fy[16];
    #pragma unroll
    for (int jj = 0; jj < 4; ++jj) {
        fx[jj*4+0] = xv[jj].x; fx[jj*4+1] = xv[jj].y;
        fx[jj*4+2] = xv[jj].z; fx[jj*4+3] = xv[jj].w;
        fy[jj*4+0] = yv[jj].x; fy[jj*4+1] = yv[jj].y;
        fy[jj*4+2] = yv[jj].z; fy[jj*4+3] = yv[jj].w;
    }

    unsigned xb0, xb1, yb0, yb1;
#ifdef HW_FP4
    // byte m = {fp4(f[2m+1])<<4 | fp4(f[2m])}: pk convention src0 -> low nibble.
    #define CVT8(dst, f, s)                                                        \
        dst = __builtin_amdgcn_cvt_scalef32_pk_fp4_f32(0u,  (f)[0]*(s), (f)[1]*(s), 1.0f, 0); \
        dst = __builtin_amdgcn_cvt_scalef32_pk_fp4_f32(dst, (f)[2]*(s), (f)[3]*(s), 1.0f, 1); \
        dst = __builtin_amdgcn_cvt_scalef32_pk_fp4_f32(dst, (f)[4]*(s), (f)[5]*(s), 1.0f, 2); \
        dst = __builtin_amdgcn_cvt_scalef32_pk_fp4_f32(dst, (f)[6]*(s), (f)[7]*(s), 1.0f, 3)
    CVT8(xb0, fx,     sx);
    CVT8(xb1, fx + 8, sx);
    CVT8(yb0, fy,     sy);
    CVT8(yb1, fy + 8, sy);
    #undef CVT8
#else
    unsigned xb[2] = {0u, 0u}, yb[2] = {0u, 0u};
    #pragma unroll
    for (int j = 0; j < 16; ++j) {
        xb[j >> 3] |= enc4(fx[j] * sx) << ((j & 7) * 4);
        yb[j >> 3] |= enc4(fy[j] * sy) << ((j & 7) * 4);
    }
    xb0 = xb[0]; xb1 = xb[1]; yb0 = yb[0]; yb1 = yb[1];
#endif

    const int p = row >> 4, r = row & 15;
    const unsigned off = (unsigned)p * 8192 + (lane >> 3) * 1024 + r * 64
                       + (lane & 7) * 8;
    *reinterpret_cast<uint2*>(xq + off) = make_uint2(xb0, xb1);
    *reinterpret_cast<uint2*>(yq + off) = make_uint2(yb0, yb1);

    if (lane == 0) sdiag[row] = sxy * invx * invy;
}

// ---------------------------------------------------------------------------
// Kernel 2 (r3 rewrite): S' = 1024 * xn*yn^T via MX-fp4, DIRECT FROM L2.
// Inputs total 4 MB (L2-resident; r1 FETCH_SIZE 9.3 MB confirmed) -> LDS
// staging/barriers/vmcnt were pure overhead (42 us idle at MfmaUtil 5.8%).
// Now: zero LDS, zero barriers. Wave tile 64x64 = 4x4 16x16x128 MFMAs, K=8
// steps fully unrolled (64 indep dwordx4 loads + 128 MFMAs straight-line);
// block = 8 waves (2x4) over 128x256 for L1 panel reuse; grid 512 blocks.
// ---------------------------------------------------------------------------
__global__ __launch_bounds__(512, 2) void gemm_exp_sums(
    const unsigned char* __restrict__ xq, const unsigned char* __restrict__ yq,
    float* __restrict__ rowsum, float* __restrict__ colsum)
{
    const int t    = threadIdx.x;
    const int lane = t & 63;
    const int wave = t >> 6;        // 0..7
    const int q    = lane >> 4;
    const int l15  = lane & 15;

    const int R0 = blockIdx.y * 128;
    const int C0 = blockIdx.x * 256;
    const int wRow = (wave >> 2) * 64;   // 0 or 64
    const int wCol = (wave & 3) * 64;    // 0,64,128,192

    f32x4_t acc[4][4];
    #pragma unroll
    for (int i = 0; i < 4; i++)
        #pragma unroll
        for (int j = 0; j < 4; j++)
            acc[i][j] = (f32x4_t){0.f, 0.f, 0.f, 0.f};

    // per-lane fragment base: panel chunk + row*64 + slot*16
    const unsigned char* pA = xq + (size_t)((R0 + wRow) >> 4) * 8192 + l15 * 64 + q * 16;
    const unsigned char* pB = yq + (size_t)((C0 + wCol) >> 4) * 8192 + l15 * 64 + q * 16;

    #pragma unroll
    for (int kb = 0; kb < 8; ++kb) {
        i32x4_t a4[4], b4[4];
        #pragma unroll
        for (int i = 0; i < 4; ++i) {
            a4[i] = *reinterpret_cast<const i32x4_t*>(pA + (size_t)i * 8192 + kb * 1024);
            b4[i] = *reinterpret_cast<const i32x4_t*>(pB + (size_t)i * 8192 + kb * 1024);
        }
        #pragma unroll
        for (int mt = 0; mt < 4; ++mt) {
            const i32x8_t af = {a4[mt][0], a4[mt][1], a4[mt][2], a4[mt][3], 0, 0, 0, 0};
            #pragma unroll
            for (int nt = 0; nt < 4; ++nt) {
                const i32x8_t bf = {b4[nt][0], b4[nt][1], b4[nt][2], b4[nt][3], 0, 0, 0, 0};
                acc[mt][nt] = __builtin_amdgcn_mfma_scale_f32_16x16x128_f8f6f4(
                    af, bf, acc[mt][nt],
                    4, 4,                       // cbsz=fp4(e2m1), blgp=fp4(e2m1)
                    0, 0x7F7F7F7F,              // A scales: E8M0 127 = 2^0
                    0, 0x7F7F7F7F);             // B scales: 2^0
            }
        }
    }

    // Epilogue: acc holds 1024*S (32x32 pre-scale) -> E = exp2(acc/(1024*TAU*ln2)).
    const float kScale = (float)(1.0 / (1024.0 * 0.07 * 0.6931471805599453));
    float csum[4] = {0.f, 0.f, 0.f, 0.f};
    #pragma unroll
    for (int mt = 0; mt < 4; ++mt) {
        float rsum[4] = {0.f, 0.f, 0.f, 0.f};
        #pragma unroll
        for (int nt = 0; nt < 4; ++nt) {
            #pragma unroll
            for (int r = 0; r < 4; ++r) {
                const float e = exp2f(acc[mt][nt][r] * kScale);
                rsum[r]  += e;
                csum[nt] += e;
            }
        }
        #pragma unroll
        for (int r = 0; r < 4; ++r) {
            float v = rsum[r];
            v += __shfl_xor(v, 1, 64);
            v += __shfl_xor(v, 2, 64);
            v += __shfl_xor(v, 4, 64);
            v += __shfl_xor(v, 8, 64);
            if (l15 == 0)
                atomicAdd(&rowsum[R0 + wRow + mt * 16 + q * 4 + r], v);
        }
    }
    #pragma unroll
    for (int nt = 0; nt < 4; ++nt) {
        float v = csum[nt];
        v += __shfl_xor(v, 16, 64);
        v += __shfl_xor(v, 32, 64);
        if (lane < 16)
            atomicAdd(&colsum[C0 + wCol + nt * 16 + l15], v);
    }
}

// ---------------------------------------------------------------------------
// Kernel 3: loss = -1/(2B) [ (2/TAU)*sum(sdiag) - sum(log(rowsum+extra))
//                            - sum(log(colsum+extra)) ]
// ---------------------------------------------------------------------------
__global__ __launch_bounds__(1024) void finalize(
    const float* __restrict__ rowsum, const float* __restrict__ colsum,
    const float* __restrict__ sdiag, float* __restrict__ out)
{
    const float extra = (float)(NB * 1e-6 + 1e-6);
    double local = 0.0;
    for (int i = threadIdx.x; i < NB; i += 1024) {
        local += (double)sdiag[i] * (2.0 / 0.07)
               - (double)logf(rowsum[i] + extra)
               - (double)logf(colsum[i] + extra);
    }
    #pragma unroll
    for (int off = 1; off < 64; off <<= 1)
        local += __shfl_xor(local, off, 64);
    __shared__ double dred[16];
    const int wave = threadIdx.x >> 6;
    if ((threadIdx.x & 63) == 0) dred[wave] = local;
    __syncthreads();
    if (threadIdx.x == 0) {
        double tot = 0.0;
        #pragma unroll
        for (int w = 0; w < 16; ++w) tot += dred[w];
        out[0] = (float)(tot * (-1.0 / (2.0 * NB)));
    }
}

// ---------------------------------------------------------------------------
extern "C" void kernel_launch(void* const* d_in, const int* in_sizes, int n_in,
                              void* d_out, int out_size, void* d_ws, size_t ws_size,
                              hipStream_t stream)
{
    const float* x = (const float*)d_in[0];
    const float* y = (const float*)d_in[1];
    float* out = (float*)d_out;

    char* ws = (char*)d_ws;
    unsigned char* xq = (unsigned char*)ws;                                 // 2 MB fp4 linear
    unsigned char* yq = (unsigned char*)(ws + (size_t)2 * 1024 * 1024);     // 2 MB fp4 linear
    float* rowsum = (float*)(ws + (size_t)8 * 1024 * 1024);                 // 16 KB
    float* colsum = rowsum + NB;                                            // 16 KB
    float* sdiag  = colsum + NB;                                            // 16 KB

    normalize_rows<<<NB / 4, 256, 0, stream>>>(x, y, xq, yq, sdiag, rowsum);

    dim3 grid(16, 32);   // x: 16 col-tiles (256), y: 32 row-tiles (128)
    gemm_exp_sums<<<grid, 512, 0, stream>>>(xq, yq, rowsum, colsum);

    finalize<<<1, 1024, 0, stream>>>(rowsum, colsum, sdiag, out);
}

// Round 4
// 95.589 us; speedup vs baseline: 1.2229x; 1.2229x over previous
//
#include <hip/hip_runtime.h>

#define NB 4096
#define DK 1024
#define EPSF 1e-6f
#define QS 32.0f          // fp4 pre-scale 2^5: normalized entries sigma=1/32 -> sigma=1

typedef __attribute__((ext_vector_type(8))) int   i32x8_t;
typedef __attribute__((ext_vector_type(4))) int   i32x4_t;
typedef __attribute__((ext_vector_type(4))) float f32x4_t;

#if defined(__has_builtin)
#if __has_builtin(__builtin_amdgcn_cvt_scalef32_pk_fp4_f32)
#define HW_FP4 1
#endif
#endif

// ---------------------------------------------------------------------------
// Global fp4 layout (swizzled, = r0): row,k -> p=row>>4, r=row&15, kb=k>>7,
// slot s=(k>>5)&3 (32 k / 16 B), nibble n=k&31:
//   byte = p*8192 + kb*1024 + r*64 + ((s^(r&3))<<4) + (n>>1), nibble n&1
// (p,kb) chunk = 1 KB contiguous -> one 64-lane x 16 B DMA (linear LDS dest,
// pre-swizzled source; fragment read applies the same s^(r&3) -> rule #21 ok).
// ---------------------------------------------------------------------------

__device__ __forceinline__ void async16(const void* g, void* lds) {
    __builtin_amdgcn_global_load_lds(
        (const __attribute__((address_space(1))) void*)g,
        (__attribute__((address_space(3))) void*)lds, 16, 0, 0);
}

// branchless e2m1 encode fallback: grid 0,.5,1,1.5,2,3,4,6.
__device__ __forceinline__ unsigned enc4(float v) {
    const float a = fabsf(v);
    unsigned c = (a >= 0.25f) + (a >= 0.75f) + (a >= 1.25f) + (a >= 1.75f)
               + (a >= 2.5f)  + (a >= 3.5f)  + (a >= 5.0f);
    return c | ((v < 0.f) ? 8u : 0u);
}

// ---------------------------------------------------------------------------
// Kernel 1: wave-per-row normalize -> fp4 e2m1 (x32) in swizzled layout;
// exact fp32 diagonal; zeroes rowsum/colsum. Lane l owns k[16l,16l+16) ->
// 16 nibbles = 8 B, one dwordx2 store per matrix. HW pk-fp4 encode.
// ---------------------------------------------------------------------------
__global__ __launch_bounds__(256) void normalize_rows(
    const float* __restrict__ x, const float* __restrict__ y,
    unsigned char* __restrict__ xq, unsigned char* __restrict__ yq,
    float* __restrict__ sdiag, float* __restrict__ zerobuf)
{
    const int t = threadIdx.x;
    const int gid = blockIdx.x * 256 + t;
    if (gid < 2 * NB) zerobuf[gid] = 0.f;   // rowsum+colsum contiguous

    const int wave = t >> 6;
    const int lane = t & 63;
    const int row  = blockIdx.x * 4 + wave;

    const float4* xr = reinterpret_cast<const float4*>(x + (size_t)row * DK);
    const float4* yr = reinterpret_cast<const float4*>(y + (size_t)row * DK);

    float4 xv[4], yv[4];
    float ssx = 0.f, ssy = 0.f, sxy = 0.f;
    #pragma unroll
    for (int jj = 0; jj < 4; ++jj) {
        xv[jj] = xr[lane * 4 + jj];
        yv[jj] = yr[lane * 4 + jj];
        ssx += xv[jj].x*xv[jj].x + xv[jj].y*xv[jj].y + xv[jj].z*xv[jj].z + xv[jj].w*xv[jj].w;
        ssy += yv[jj].x*yv[jj].x + yv[jj].y*yv[jj].y + yv[jj].z*yv[jj].z + yv[jj].w*yv[jj].w;
        sxy += xv[jj].x*yv[jj].x + xv[jj].y*yv[jj].y + xv[jj].z*yv[jj].z + xv[jj].w*yv[jj].w;
    }
    #pragma unroll
    for (int off = 1; off < 64; off <<= 1) {
        ssx += __shfl_xor(ssx, off, 64);
        ssy += __shfl_xor(ssy, off, 64);
        sxy += __shfl_xor(sxy, off, 64);
    }
    const float invx = 1.0f / fmaxf(sqrtf(ssx), EPSF);
    const float invy = 1.0f / fmaxf(sqrtf(ssy), EPSF);
    const float sx = invx * QS;
    const float sy = invy * QS;

    float fx[16], fy[16];
    #pragma unroll
    for (int jj = 0; jj < 4; ++jj) {
        fx[jj*4+0] = xv[jj].x; fx[jj*4+1] = xv[jj].y;
        fx[jj*4+2] = xv[jj].z; fx[jj*4+3] = xv[jj].w;
        fy[jj*4+0] = yv[jj].x; fy[jj*4+1] = yv[jj].y;
        fy[jj*4+2] = yv[jj].z; fy[jj*4+3] = yv[jj].w;
    }

    unsigned xb0, xb1, yb0, yb1;
#ifdef HW_FP4
    // byte m = {fp4(f[2m+1])<<4 | fp4(f[2m])}: pk convention src0 -> low nibble.
    #define CVT8(dst, f, s)                                                        \
        dst = __builtin_amdgcn_cvt_scalef32_pk_fp4_f32(0u,  (f)[0]*(s), (f)[1]*(s), 1.0f, 0); \
        dst = __builtin_amdgcn_cvt_scalef32_pk_fp4_f32(dst, (f)[2]*(s), (f)[3]*(s), 1.0f, 1); \
        dst = __builtin_amdgcn_cvt_scalef32_pk_fp4_f32(dst, (f)[4]*(s), (f)[5]*(s), 1.0f, 2); \
        dst = __builtin_amdgcn_cvt_scalef32_pk_fp4_f32(dst, (f)[6]*(s), (f)[7]*(s), 1.0f, 3)
    CVT8(xb0, fx,     sx);
    CVT8(xb1, fx + 8, sx);
    CVT8(yb0, fy,     sy);
    CVT8(yb1, fy + 8, sy);
    #undef CVT8
#else
    unsigned xb[2] = {0u, 0u}, yb[2] = {0u, 0u};
    #pragma unroll
    for (int j = 0; j < 16; ++j) {
        xb[j >> 3] |= enc4(fx[j] * sx) << ((j & 7) * 4);
        yb[j >> 3] |= enc4(fy[j] * sy) << ((j & 7) * 4);
    }
    xb0 = xb[0]; xb1 = xb[1]; yb0 = yb[0]; yb1 = yb[1];
#endif

    const int p = row >> 4, r = row & 15;
    const unsigned off = (unsigned)p * 8192 + (lane >> 3) * 1024 + r * 64
                       + ((((lane & 7) >> 1) ^ (r & 3)) << 4) + (lane & 1) * 8;
    *reinterpret_cast<uint2*>(xq + off) = make_uint2(xb0, xb1);
    *reinterpret_cast<uint2*>(yq + off) = make_uint2(yb0, yb1);

    if (lane == 0) sdiag[row] = sxy * invx * invy;
}

// ---------------------------------------------------------------------------
// Kernel 2 (r4): faithful m97/m153 structure (learn_hip: 2878 TF MX-fp4).
//   128x128 tile, 256 threads / 4 waves (each 64x64 = 4x4 16x16 accs),
//   grid 32x32 = 1024 blocks = 4 blocks/CU (32 KB LDS, <=128 VGPR),
//   double-buffered global_load_lds, ONE full-drain barrier per K-step.
// All prior variants (8-wave, 1-2 blocks/CU, hand vmcnt) sat at ~40-52 us
// with MfmaUtil ~6%; the proven structure's lever is 16 waves/CU across 4
// independent barrier domains -> cross-block overlap hides the drain (m114).
// ---------------------------------------------------------------------------
__global__ __launch_bounds__(256, 4) void gemm_exp_sums(
    const unsigned char* __restrict__ xq, const unsigned char* __restrict__ yq,
    float* __restrict__ rowsum, float* __restrict__ colsum)
{
    __shared__ __align__(16) unsigned char LDS[2][16384];  // [buf][A:0-8K | B:8K-16K]

    const int t    = threadIdx.x;
    const int lane = t & 63;
    const int wave = t >> 6;        // 0..3
    const int q    = lane >> 4;
    const int l15  = lane & 15;

    const int R0 = blockIdx.y * 128;
    const int C0 = blockIdx.x * 128;
    const int wRow = (wave >> 1) * 64;   // 0 or 64
    const int wCol = (wave & 1) * 64;    // 0 or 64

    f32x4_t acc[4][4];
    #pragma unroll
    for (int i = 0; i < 4; i++)
        #pragma unroll
        for (int j = 0; j < 4; j++)
            acc[i][j] = (f32x4_t){0.f, 0.f, 0.f, 0.f};

    // wave w stages A panels {2w,2w+1} and B panels {2w,2w+1}: 4 DMAs/lane/stage
    const unsigned char* srcA =
        xq + (size_t)((R0 >> 4) + 2 * wave) * 8192 + lane * 16;
    const unsigned char* srcB =
        yq + (size_t)((C0 >> 4) + 2 * wave) * 8192 + lane * 16;

    auto issue = [&](int kb, int buf) {
        #pragma unroll
        for (int pp = 0; pp < 2; ++pp) {
            async16(srcA + pp * 8192 + kb * 1024,
                    &LDS[buf][(2 * wave + pp) * 1024]);
            async16(srcB + pp * 8192 + kb * 1024,
                    &LDS[buf][8192 + (2 * wave + pp) * 1024]);
        }
    };

    issue(0, 0);

    const int sl = (q ^ (l15 & 3)) << 4;   // swizzled 16-B slot within row

    #pragma unroll 1
    for (int kb = 0; kb < 8; ++kb) {
        const int buf = kb & 1;
        // drain this buf's DMAs; barrier also fences prev iter's reads of buf^1
        __builtin_amdgcn_s_waitcnt(0xF70);   // vmcnt(0), lgkm/exp no-wait
        __syncthreads();
        if (kb < 7) issue(kb + 1, buf ^ 1);  // prefetch flies during compute

        i32x8_t bfr[4];
        #pragma unroll
        for (int nt = 0; nt < 4; ++nt) {
            const i32x4_t v = *reinterpret_cast<const i32x4_t*>(
                &LDS[buf][8192 + ((wCol >> 4) + nt) * 1024 + l15 * 64 + sl]);
            bfr[nt][0] = v[0]; bfr[nt][1] = v[1]; bfr[nt][2] = v[2]; bfr[nt][3] = v[3];
            bfr[nt][4] = 0;    bfr[nt][5] = 0;    bfr[nt][6] = 0;    bfr[nt][7] = 0;
        }
        #pragma unroll
        for (int mt = 0; mt < 4; ++mt) {
            const i32x4_t v = *reinterpret_cast<const i32x4_t*>(
                &LDS[buf][((wRow >> 4) + mt) * 1024 + l15 * 64 + sl]);
            i32x8_t af;
            af[0] = v[0]; af[1] = v[1]; af[2] = v[2]; af[3] = v[3];
            af[4] = 0;    af[5] = 0;    af[6] = 0;    af[7] = 0;
            #pragma unroll
            for (int nt = 0; nt < 4; ++nt)
                acc[mt][nt] = __builtin_amdgcn_mfma_scale_f32_16x16x128_f8f6f4(
                    af, bfr[nt], acc[mt][nt],
                    4, 4,                       // cbsz=fp4(e2m1), blgp=fp4(e2m1)
                    0, 0x7F7F7F7F,              // A scales: E8M0 127 = 2^0
                    0, 0x7F7F7F7F);             // B scales: 2^0
        }
    }

    // Epilogue: acc holds 1024*S (32x32 pre-scale) -> E = exp2(acc/(1024*TAU*ln2)).
    const float kScale = (float)(1.0 / (1024.0 * 0.07 * 0.6931471805599453));
    float csum[4] = {0.f, 0.f, 0.f, 0.f};
    #pragma unroll
    for (int mt = 0; mt < 4; ++mt) {
        float rsum[4] = {0.f, 0.f, 0.f, 0.f};
        #pragma unroll
        for (int nt = 0; nt < 4; ++nt) {
            #pragma unroll
            for (int r = 0; r < 4; ++r) {
                const float e = exp2f(acc[mt][nt][r] * kScale);
                rsum[r]  += e;
                csum[nt] += e;
            }
        }
        #pragma unroll
        for (int r = 0; r < 4; ++r) {
            float v = rsum[r];
            v += __shfl_xor(v, 1, 64);
            v += __shfl_xor(v, 2, 64);
            v += __shfl_xor(v, 4, 64);
            v += __shfl_xor(v, 8, 64);
            if (l15 == 0)
                atomicAdd(&rowsum[R0 + wRow + mt * 16 + q * 4 + r], v);
        }
    }
    #pragma unroll
    for (int nt = 0; nt < 4; ++nt) {
        float v = csum[nt];
        v += __shfl_xor(v, 16, 64);
        v += __shfl_xor(v, 32, 64);
        if (lane < 16)
            atomicAdd(&colsum[C0 + wCol + nt * 16 + l15], v);
    }
}

// ---------------------------------------------------------------------------
// Kernel 3: loss = -1/(2B) [ (2/TAU)*sum(sdiag) - sum(log(rowsum+extra))
//                            - sum(log(colsum+extra)) ]
// ---------------------------------------------------------------------------
__global__ __launch_bounds__(1024) void finalize(
    const float* __restrict__ rowsum, const float* __restrict__ colsum,
    const float* __restrict__ sdiag, float* __restrict__ out)
{
    const float extra = (float)(NB * 1e-6 + 1e-6);
    double local = 0.0;
    for (int i = threadIdx.x; i < NB; i += 1024) {
        local += (double)sdiag[i] * (2.0 / 0.07)
               - (double)logf(rowsum[i] + extra)
               - (double)logf(colsum[i] + extra);
    }
    #pragma unroll
    for (int off = 1; off < 64; off <<= 1)
        local += __shfl_xor(local, off, 64);
    __shared__ double dred[16];
    const int wave = threadIdx.x >> 6;
    if ((threadIdx.x & 63) == 0) dred[wave] = local;
    __syncthreads();
    if (threadIdx.x == 0) {
        double tot = 0.0;
        #pragma unroll
        for (int w = 0; w < 16; ++w) tot += dred[w];
        out[0] = (float)(tot * (-1.0 / (2.0 * NB)));
    }
}

// ---------------------------------------------------------------------------
extern "C" void kernel_launch(void* const* d_in, const int* in_sizes, int n_in,
                              void* d_out, int out_size, void* d_ws, size_t ws_size,
                              hipStream_t stream)
{
    const float* x = (const float*)d_in[0];
    const float* y = (const float*)d_in[1];
    float* out = (float*)d_out;

    char* ws = (char*)d_ws;
    unsigned char* xq = (unsigned char*)ws;                                 // 2 MB fp4 swizzled
    unsigned char* yq = (unsigned char*)(ws + (size_t)2 * 1024 * 1024);     // 2 MB fp4 swizzled
    float* rowsum = (float*)(ws + (size_t)8 * 1024 * 1024);                 // 16 KB
    float* colsum = rowsum + NB;                                            // 16 KB
    float* sdiag  = colsum + NB;                                            // 16 KB

    normalize_rows<<<NB / 4, 256, 0, stream>>>(x, y, xq, yq, sdiag, rowsum);

    dim3 grid(32, 32);   // 128x128 tiles, 1024 blocks = 4/CU
    gemm_exp_sums<<<grid, 256, 0, stream>>>(xq, yq, rowsum, colsum);

    finalize<<<1, 1024, 0, stream>>>(rowsum, colsum, sdiag, out);
}